// Round 8
// baseline (191.643 us; speedup 1.0000x reference)
//
#include <hip/hip_runtime.h>
#include <stdint.h>

// ContrastiveLossInBatch: loss = mean_i [ lse_j(q_i.k_j/T) - q_i.k_i/T ],
// N=8192, C=256, T=0.07. Fused MFMA GEMM + per-lane online logsumexp (base 2).
//
// R8: R0/R2/R6/R7 all pin at 47-51us. Counters are ADDITIVE: MFMA 28%x47 ~
// 13.5us (= floor), VALU 38%x47 ~ 18us (= LSE arithmetic), LDS/waits ~12us;
// 16.6+18+12 ~ 47 => ZERO cross-pipe overlap. Cause: phase-locking — in-order
// per-wave issue makes each wave serial {ds,MFMA,LSE}; the per-tile barrier
// forces all 4 waves of a block into the SAME phase, so co-resident waves
// contend for one pipe instead of overlapping different pipes. R7's counted
// vmcnt couldn't fix this (it only moved the stage wait).
// Fix: remove LDS and ALL barriers. k is 4 MiB (fits every XCD L2); a block's
// 16 KiB tile fits L1, which multicasts the 4-wave reuse. Each wave streams
// B-fragments global->register (b[8], 16B/lane, 64B-segment coalesced) and
// runs free — MFMA/LSE phases of independent waves overlap by construction.
// s_setprio(1) around MFMA clusters (T5's independent-wave regime).
// Compute/mappings/LSE/store bit-identical to R6/R7 (harness-verified);
// only the B-source changed (same elements, from global instead of LDS).
//
// Workspace layout (9.03 MiB):
//   [0,       4 MiB)  q in f16, pre-scaled by (1/T)*log2(e)
//   [4 MiB,   8 MiB)  k in f16
//   [8 MiB, +512 KiB) per-(split,row) running max M   (SPLIT*N floats)
//   ...     +512 KiB  per-(split,row) running sum S
//   ...     +32 KiB   per-row diagonal (base-2 units)
//   ...               32 partial row-loss sums

#define N_ROWS 8192
#define C_DIM  256
#define BN     32
#define SPLIT  16
#define JCOLS  (N_ROWS / SPLIT)   // 512 columns per split
#define JTILES (JCOLS / BN)       // 16 k-tiles per block
#define BLK_ROWS 128              // 4 waves * 32 rows
#define TILE_B  (BN * C_DIM * 2)  // 16 KiB per k-tile

typedef __attribute__((ext_vector_type(8)))  _Float16 half8;
typedef __attribute__((ext_vector_type(4)))  _Float16 half4;
typedef __attribute__((ext_vector_type(4)))  float    f32x4;

#if __has_builtin(__builtin_amdgcn_exp2f)
#define EXP2(x) __builtin_amdgcn_exp2f(x)
#else
#define EXP2(x) exp2f(x)
#endif
#if __has_builtin(__builtin_amdgcn_logf)
#define LOG2(x) __builtin_amdgcn_logf(x)
#else
#define LOG2(x) log2f(x)
#endif

// ---- fp32 -> f16 conversion + per-row diagonal -----------------------------
__global__ void cvt_kernel(const float* __restrict__ q, const float* __restrict__ k,
                           _Float16* __restrict__ qh, _Float16* __restrict__ kh,
                           float* __restrict__ pP) {
  const float QS = 20.60992915555663f;  // (1/0.07) * log2(e)
  int i = blockIdx.x * 256 + threadIdx.x;
  float4 qv = ((const float4*)q)[i];
  float4 kv = ((const float4*)k)[i];
  half4 qo, ko;
  qo[0] = (_Float16)(qv.x * QS); qo[1] = (_Float16)(qv.y * QS);
  qo[2] = (_Float16)(qv.z * QS); qo[3] = (_Float16)(qv.w * QS);
  ko[0] = (_Float16)kv.x; ko[1] = (_Float16)kv.y;
  ko[2] = (_Float16)kv.z; ko[3] = (_Float16)kv.w;
  ((half4*)qh)[i] = qo;
  ((half4*)kh)[i] = ko;

  float d = (float)qo[0] * (float)ko[0];
  d = fmaf((float)qo[1], (float)ko[1], d);
  d = fmaf((float)qo[2], (float)ko[2], d);
  d = fmaf((float)qo[3], (float)ko[3], d);
#pragma unroll
  for (int off = 1; off < 64; off <<= 1) d += __shfl_xor(d, off);
  if ((threadIdx.x & 63) == 0) pP[i >> 6] = d;   // row = global_thread / 64
}

// ---- main fused GEMM + per-lane online base-2 logsumexp --------------------
// Block: 256 threads = 4 INDEPENDENT waves (no barriers, no LDS); wave owns
// 32 rows as 2 x 16-row fragments (16x16x32 MFMA, R0/R6-verified mappings):
//  A: lane holds q[row0 + rf*16 + l15][ks*32 + lg*8 .. +8)
//  B: lane loads k[j0  + cf*16 + l15][ks*32 + lg*8 .. +8) straight from
//     global (per-lane addr = base + l15*512 + lg*16 + ks*64; 16 x 64B
//     segments per load instruction; L1 multicasts the 4-wave tile reuse)
//  C/D: col = cf*16 + l15, row = row0 + rf*16 + lg*4 + j
__launch_bounds__(256, 2)
__global__ void sim_lse_kernel(const _Float16* __restrict__ qh,
                               const _Float16* __restrict__ kh,
                               float* __restrict__ pM,
                               float* __restrict__ pS) {
  const int tid  = threadIdx.x;
  const int lane = tid & 63;
  const int wave = tid >> 6;
  const int l15  = lane & 15;
  const int lg   = lane >> 4;       // quad group 0..3

  const int bid  = blockIdx.x;
  const int sp   = bid & (SPLIT - 1);
  const int rb   = bid >> 4;
  const int row0 = rb * BLK_ROWS + wave * 32;

  // A fragments resident for whole kernel: 2 x 8 x half8 = 64 VGPR
  half8 a[2][8];
#pragma unroll
  for (int rf = 0; rf < 2; ++rf) {
    const _Float16* qr = qh + (size_t)(row0 + rf * 16 + l15) * C_DIM + lg * 8;
#pragma unroll
    for (int ks = 0; ks < 8; ++ks) a[rf][ks] = *(const half8*)(qr + ks * 32);
  }

  // Per-lane LSE state: slot s = rf*4 + j  ->  row = row0 + rf*16 + lg*4 + j
  float M[8], S[8];
#pragma unroll
  for (int s = 0; s < 8; ++s) { M[s] = -__builtin_inff(); S[s] = 0.f; }

  // per-lane global base for B-fragments (bytes); cf=1 is +16 rows
  const char* kb0 = (const char*)(kh + (size_t)sp * JCOLS * C_DIM)
                    + l15 * 512 + lg * 16;
  const char* kb1 = kb0 + 16 * 512;

  for (int jt = 0; jt < JTILES; ++jt) {
    f32x4 acc00 = {0.f,0.f,0.f,0.f}, acc01 = {0.f,0.f,0.f,0.f};
    f32x4 acc10 = {0.f,0.f,0.f,0.f}, acc11 = {0.f,0.f,0.f,0.f};

    // ---- cf = 0 half: load 8 fragments, 16 MFMAs ------------------------
    {
      half8 b[8];
#pragma unroll
      for (int ks = 0; ks < 8; ++ks) b[ks] = *(const half8*)(kb0 + ks * 64);
      __builtin_amdgcn_s_setprio(1);
#pragma unroll
      for (int ks = 0; ks < 8; ++ks) {
        acc00 = __builtin_amdgcn_mfma_f32_16x16x32_f16(a[0][ks], b[ks], acc00, 0, 0, 0);
        acc10 = __builtin_amdgcn_mfma_f32_16x16x32_f16(a[1][ks], b[ks], acc10, 0, 0, 0);
      }
      __builtin_amdgcn_s_setprio(0);
    }
    // ---- cf = 1 half ----------------------------------------------------
    {
      half8 b[8];
#pragma unroll
      for (int ks = 0; ks < 8; ++ks) b[ks] = *(const half8*)(kb1 + ks * 64);
      __builtin_amdgcn_s_setprio(1);
#pragma unroll
      for (int ks = 0; ks < 8; ++ks) {
        acc01 = __builtin_amdgcn_mfma_f32_16x16x32_f16(a[0][ks], b[ks], acc01, 0, 0, 0);
        acc11 = __builtin_amdgcn_mfma_f32_16x16x32_f16(a[1][ks], b[ks], acc11, 0, 0, 0);
      }
      __builtin_amdgcn_s_setprio(0);
    }
    kb0 += TILE_B; kb1 += TILE_B;

    // ---- per-lane online logsumexp: merge the row's two cols in one step --
#pragma unroll
    for (int j = 0; j < 4; ++j) {
      {  // rf = 0, slot j
        float v0 = acc00[j], v1 = acc01[j];
        float newM  = fmaxf(fmaxf(M[j], v0), v1);   // v_max3
        float alpha = EXP2(M[j] - newM);            // exp2(-inf)=0 handles init
        float p = EXP2(v0 - newM) + EXP2(v1 - newM);
        S[j] = fmaf(S[j], alpha, p);
        M[j] = newM;
      }
      {  // rf = 1, slot 4 + j
        float v0 = acc10[j], v1 = acc11[j];
        float newM  = fmaxf(fmaxf(M[4 + j], v0), v1);
        float alpha = EXP2(M[4 + j] - newM);
        float p = EXP2(v0 - newM) + EXP2(v1 - newM);
        S[4 + j] = fmaf(S[4 + j], alpha, p);
        M[4 + j] = newM;
      }
    }
  }

  // ---- one-time 16-lane butterfly merge of (M,S) --------------------------
#pragma unroll
  for (int s = 0; s < 8; ++s) {
#pragma unroll
    for (int off = 1; off < 16; off <<= 1) {
      float Mo = __shfl_xor(M[s], off);
      float So = __shfl_xor(S[s], off);
      float nm = fmaxf(M[s], Mo);
      S[s] = S[s] * EXP2(M[s] - nm) + So * EXP2(Mo - nm);
      M[s] = nm;
    }
  }

  if (l15 == 0) {   // 4 lanes per wave (lg = 0..3), 8 rows each = 32 rows
#pragma unroll
    for (int s = 0; s < 8; ++s) {
      int grow = row0 + (s >> 2) * 16 + lg * 4 + (s & 3);
      pM[(size_t)sp * N_ROWS + grow] = M[s];
      pS[(size_t)sp * N_ROWS + grow] = S[s];
    }
  }
}

// ---- stage 1: 32 blocks, one thread per row; partial sums -----------------
__global__ void finish1_kernel(const float* __restrict__ pM, const float* __restrict__ pS,
                               const float* __restrict__ pP, float* __restrict__ pPart) {
  const int tid = threadIdx.x;
  const int r = blockIdx.x * 256 + tid;
  float m = -__builtin_inff();
#pragma unroll
  for (int s = 0; s < SPLIT; ++s) m = fmaxf(m, pM[s * N_ROWS + r]);
  float ssum = 0.f;
#pragma unroll
  for (int s = 0; s < SPLIT; ++s)
    ssum = fmaf(pS[s * N_ROWS + r], EXP2(pM[s * N_ROWS + r] - m), ssum);
  float accl = (m + LOG2(ssum)) - pP[r];   // row loss in base-2 units
#pragma unroll
  for (int off = 1; off < 64; off <<= 1) accl += __shfl_xor(accl, off);
  __shared__ float wsum[4];
  if ((tid & 63) == 0) wsum[tid >> 6] = accl;
  __syncthreads();
  if (tid == 0)
    pPart[blockIdx.x] = wsum[0] + wsum[1] + wsum[2] + wsum[3];
}

// ---- stage 2: reduce 32 partials, convert base-2 -> nats, mean ------------
__global__ void finish2_kernel(const float* __restrict__ pPart, float* __restrict__ out) {
  const int tid = threadIdx.x;   // 64 threads
  float v = (tid < 32) ? pPart[tid] : 0.f;
#pragma unroll
  for (int off = 1; off < 64; off <<= 1) v += __shfl_xor(v, off);
  if (tid == 0)
    out[0] = v * (0.69314718055994531f / (float)N_ROWS);  // ln2 * mean
}

extern "C" void kernel_launch(void* const* d_in, const int* in_sizes, int n_in,
                              void* d_out, int out_size, void* d_ws, size_t ws_size,
                              hipStream_t stream) {
  const float* q = (const float*)d_in[0];
  const float* k = (const float*)d_in[1];
  float* out = (float*)d_out;
  char* ws = (char*)d_ws;

  _Float16* qh = (_Float16*)ws;                                  // 4 MiB
  _Float16* kh = (_Float16*)(ws + (size_t)N_ROWS * C_DIM * 2);   // 4 MiB
  float* pM = (float*)(ws + (size_t)N_ROWS * C_DIM * 4);         // 512 KiB
  float* pS = pM + SPLIT * N_ROWS;                               // 512 KiB
  float* pP = pS + SPLIT * N_ROWS;                               // 32 KiB
  float* pPart = pP + N_ROWS;                                    // 128 B

  cvt_kernel<<<dim3(N_ROWS * C_DIM / 4 / 256), dim3(256), 0, stream>>>(q, k, qh, kh, pP);
  sim_lse_kernel<<<dim3((N_ROWS / BLK_ROWS) * SPLIT), dim3(256), 0, stream>>>(qh, kh, pM, pS);
  finish1_kernel<<<dim3(N_ROWS / 256), dim3(256), 0, stream>>>(pM, pS, pP, pPart);
  finish2_kernel<<<dim3(1), dim3(64), 0, stream>>>(pPart, out);
}